// Round 3
// baseline (603.832 us; speedup 1.0000x reference)
//
#include <hip/hip_runtime.h>

#define N_NODES 100000
#define N_EDGES 6400000
#define IN_DIM 10
#define HIDDEN 16

#define BKT_SHIFT 7
#define BKT_NODES 128                       // nodes per bucket; 1 pass-2 block owns 1 bucket
#define NBKT 782                            // ceil(100000/128)
#define RBIN 11                             // LDS slots per (block,bin): fill λ=5.24, P(>11)~0.8%
#define EPB 4096                            // edges per pass-1 block (8/thread, 2x uint4 pairs)
#define NB1 ((N_EDGES + EPB - 1) / EPB)     // 1563 blocks
#define CAPB 12288                          // region slots per bucket (mean ~10.5k, +11 sigma)
#define CAPO 256                            // overflow slots per bucket (expect ~18/bucket)
#define XELEMS (N_NODES * IN_DIM)
#define XE_PER_BLK ((XELEMS + NB1 - 1) / NB1)  // 640
#define SENT 0xFFFFFFFFu                    // pad sentinel; valid packs < 0x01000000

typedef unsigned uv4 __attribute__((ext_vector_type(4)));
typedef int iv4 __attribute__((ext_vector_type(4)));
typedef float fv4 __attribute__((ext_vector_type(4)));

__device__ __forceinline__ float bf_lo(unsigned u) { return __uint_as_float(u << 16); }
__device__ __forceinline__ float bf_hi(unsigned u) { return __uint_as_float(u & 0xffff0000u); }

// ---------------- Pass 1: xpack prologue + bin edges; 16B-aligned drain runs ----------------
__global__ __launch_bounds__(512, 8) void bin_edges_xpack(const int* __restrict__ src,
                                                          const int* __restrict__ dst,
                                                          const float* __restrict__ x,
                                                          int* __restrict__ gcur,
                                                          int* __restrict__ gover,
                                                          unsigned* __restrict__ region,
                                                          unsigned* __restrict__ over,
                                                          unsigned short* __restrict__ xp) {
    __shared__ int lcur[NBKT];               // 3.1 KB
    __shared__ unsigned lbin[NBKT * RBIN];   // 34.4 KB; total 37.5 KB -> 4 blocks/CU
    int t = threadIdx.x;
    for (int b = t; b < NBKT; b += 512) lcur[b] = 0;

    // xpack slice: x fp32 (40B rows) -> bf16 rows at 32B stride (1 line per gather)
    int xbase = blockIdx.x * XE_PER_BLK;
    int xend = min(xbase + XE_PER_BLK, XELEMS);
    for (int e = xbase + t; e < xend; e += 512) {
        int row = e / 10, k = e - row * 10;
        unsigned bits = __float_as_uint(__builtin_nontemporal_load(&x[e]));
        xp[(size_t)row * 16 + k] = (unsigned short)((bits + 0x8000u) >> 16);
    }
    __syncthreads();

    // binning: uint4 edge loads (4 edges/thread/iter), 1 LDS atomic + 1 LDS store per edge
    int base = blockIdx.x * EPB;
    int end = min(base + EPB, N_EDGES);
#define BIN1(ss, dd)                                                                     \
    {                                                                                    \
        int s = (ss), d = (dd);                                                          \
        if ((unsigned)s < N_NODES && (unsigned)d < N_NODES) {                            \
            unsigned pack = (unsigned)s | ((unsigned)(d & (BKT_NODES - 1)) << 17);       \
            int bb = d >> BKT_SHIFT;                                                     \
            int pos = atomicAdd(&lcur[bb], 1);                                           \
            if (pos < RBIN) {                                                            \
                lbin[bb * RBIN + pos] = pack;                                            \
            } else {                                                                     \
                int gg = atomicAdd(&gover[bb], 1);                                       \
                if (gg < CAPO) over[(size_t)bb * CAPO + gg] = pack;                      \
            }                                                                            \
        }                                                                                \
    }
    for (int i = base + (t << 2); i < end; i += 2048) {
        iv4 sv = __builtin_nontemporal_load((const iv4*)(src + i));
        iv4 dv = __builtin_nontemporal_load((const iv4*)(dst + i));
        BIN1(sv.x, dv.x); BIN1(sv.y, dv.y); BIN1(sv.z, dv.z); BIN1(sv.w, dv.w);
    }
    __syncthreads();

    // drain: cursor advances in multiples of 4 slots -> every run is a 16B-aligned
    // uint4-store burst; pad slots carry SENT, filtered free in pass 2 (~1.28x inflate).
    for (int b = t; b < NBKT; b += 512) {
        int f = min(lcur[b], RBIN);
        if (f > 0) {
            int fp = (f + 3) & ~3;                   // 4, 8 or 12
            int g = atomicAdd(&gcur[b], fp);         // stays 4-aligned
            if (g + fp <= CAPB) {
                unsigned* dp = region + (size_t)b * CAPB;
                for (int j = 0; j < fp; j += 4) {
                    uint4 v;
                    v.x = (j + 0 < f) ? lbin[b * RBIN + j + 0] : SENT;
                    v.y = (j + 1 < f) ? lbin[b * RBIN + j + 1] : SENT;
                    v.z = (j + 2 < f) ? lbin[b * RBIN + j + 2] : SENT;
                    v.w = (j + 3 < f) ? lbin[b * RBIN + j + 3] : SENT;
                    *(uint4*)&dp[g + j] = v;         // 16B-aligned store
                }
            }
        }
    }
}

// ---------------- Pass 2: one block per bucket; direct LDS f32-atomic accumulate ----------------
// Round-3 restructure: the old 4-sub-block design read every bucket's region stream
// 4x and filtered away 3/4 of it, then round-tripped records through a 34.8KB LDS
// sort buffer. Now each block owns a whole 128-node bucket: region read ONCE, each
// record does its gather + 11 ds_add_f32 straight into accf[128][11] (stride 11 is
// bank-coprime; slot 10 is the count). LDS drops to 7KB -> 4 blocks/CU by threads.
// region/over stay nt (read-once streams) so the 3.2MB xp table stays L2-resident.
#define GATH(r, p, qq)                                                                   \
    {                                                                                    \
        unsigned sid = ((r) == SENT) ? 0u : ((r) & 0x1FFFFu);  /* pads hit hot line */   \
        const unsigned* pp = (const unsigned*)(xp + (size_t)sid * 16);                   \
        p = *(const uint4*)pp;                                                           \
        qq = pp[4];                                                                      \
    }
#define ACCUM(r, p, qq)                                                                  \
    if ((r) != SENT) {                                                                   \
        int nd = ((r) >> 17) & (BKT_NODES - 1);                                          \
        float* a = accf[nd];                                                             \
        atomicAdd(a + 0, bf_lo(p.x)); atomicAdd(a + 1, bf_hi(p.x));                      \
        atomicAdd(a + 2, bf_lo(p.y)); atomicAdd(a + 3, bf_hi(p.y));                      \
        atomicAdd(a + 4, bf_lo(p.z)); atomicAdd(a + 5, bf_hi(p.z));                      \
        atomicAdd(a + 6, bf_lo(p.w)); atomicAdd(a + 7, bf_hi(p.w));                      \
        atomicAdd(a + 8, bf_lo(qq));  atomicAdd(a + 9, bf_hi(qq));                       \
        atomicAdd(a + 10, 1.0f);                                                         \
    }

__global__ __launch_bounds__(512, 8) void bucket_accum_out(const unsigned short* __restrict__ xp,
                                                           const float* __restrict__ x,
                                                           const int* __restrict__ gcur,
                                                           const int* __restrict__ gover,
                                                           const unsigned* __restrict__ region,
                                                           const unsigned* __restrict__ over,
                                                           const float* __restrict__ W_l,
                                                           const float* __restrict__ b_l,
                                                           const float* __restrict__ W_r,
                                                           float* __restrict__ out) {
    __shared__ float accf[BKT_NODES][IN_DIM + 1];   // 5.5 KB, stride 11 bank-coprime
    __shared__ float sWl[IN_DIM * HIDDEN], sWr[IN_DIM * HIDDEN], sb[HIDDEN];

    int b = blockIdx.x;
    int t = threadIdx.x;
    for (int i = t; i < BKT_NODES * (IN_DIM + 1); i += 512) ((float*)accf)[i] = 0.0f;
    if (t < IN_DIM * HIDDEN) { sWl[t] = W_l[t]; sWr[t] = W_r[t]; }
    if (t < HIDDEN) sb[t] = b_l[t];
    __syncthreads();

    int n = min(gcur[b], CAPB);                  // multiple of 4 -> clean uint4 walk
    int n4 = n >> 2;
    const uv4* reg4 = (const uv4*)(region + (size_t)b * CAPB);

    // single region walk: 4 independent gathers in flight per uint4, then the adds
    for (int i = t; i < n4; i += 512) {
        uv4 rv = __builtin_nontemporal_load(&reg4[i]);
        uint4 p0, p1, p2, p3; unsigned q0, q1, q2, q3;
        GATH(rv.x, p0, q0); GATH(rv.y, p1, q1); GATH(rv.z, p2, q2); GATH(rv.w, p3, q3);
        ACCUM(rv.x, p0, q0); ACCUM(rv.y, p1, q1); ACCUM(rv.z, p2, q2); ACCUM(rv.w, p3, q3);
    }
    // overflow list (rare, ~18/bucket)
    int m = min(gover[b], CAPO);
    const unsigned* ov = over + (size_t)b * CAPO;
    for (int i = t; i < m; i += 512) {
        unsigned r = __builtin_nontemporal_load(&ov[i]);
        uint4 p; unsigned qq;
        GATH(r, p, qq);
        ACCUM(r, p, qq);
    }
    __syncthreads();

    // fused epilogue: mean + GEMV + bias; exact fp32 root term. 4 threads/node, 4 h each.
    {
        int nl = t >> 2;                         // 0..127
        int hq = (t & 3) << 2;                   // 0,4,8,12
        int node = b * BKT_NODES + nl;
        if (node < N_NODES) {
            float inv = 1.0f / fmaxf(accf[nl][IN_DIM], 1.0f);
            const float* xr = x + (size_t)node * IN_DIM;
            float o0 = sb[hq], o1 = sb[hq + 1], o2 = sb[hq + 2], o3 = sb[hq + 3];
#pragma unroll
            for (int k = 0; k < IN_DIM; ++k) {
                float m2 = accf[nl][k] * inv;    // LDS broadcast across the 4 lanes
                float xk = xr[k];                // same line for 4 lanes -> 1 req
                const float* wl = &sWl[k * HIDDEN + hq];
                const float* wr = &sWr[k * HIDDEN + hq];
                o0 += m2 * wl[0] + xk * wr[0];
                o1 += m2 * wl[1] + xk * wr[1];
                o2 += m2 * wl[2] + xk * wr[2];
                o3 += m2 * wl[3] + xk * wr[3];
            }
            fv4 o = {o0, o1, o2, o3};
            __builtin_nontemporal_store(o, (fv4*)(out + (size_t)node * HIDDEN + hq));
        }
    }
}

// ---------------- fallback (round-1 style, correct, slow) for tiny ws ----------------
__global__ void sage_scatter_fb(const float* __restrict__ x, const int* __restrict__ src,
                                const int* __restrict__ dst, float* __restrict__ summed,
                                float* __restrict__ counts) {
    int e = blockIdx.x * blockDim.x + threadIdx.x;
    if (e >= N_EDGES) return;
    int s = src[e], d = dst[e];
    if ((unsigned)s >= N_NODES || (unsigned)d >= N_NODES) return;
    const float* xs = x + (size_t)s * IN_DIM;
    float* sm = summed + (size_t)d * IN_DIM;
#pragma unroll
    for (int k = 0; k < IN_DIM; ++k) atomicAdd(&sm[k], xs[k]);
    atomicAdd(&counts[d], 1.0f);
}

__global__ void sage_out_fb(const float* __restrict__ x, const float* __restrict__ summed,
                            const float* __restrict__ counts, const float* __restrict__ W_l,
                            const float* __restrict__ b_l, const float* __restrict__ W_r,
                            float* __restrict__ out) {
    __shared__ float sWl[IN_DIM * HIDDEN], sWr[IN_DIM * HIDDEN], sb[HIDDEN];
    int t = threadIdx.x;
    if (t < IN_DIM * HIDDEN) { sWl[t] = W_l[t]; sWr[t] = W_r[t]; }
    if (t < HIDDEN) sb[t] = b_l[t];
    __syncthreads();
    int tid = blockIdx.x * blockDim.x + t;
    if (tid >= N_NODES * HIDDEN) return;
    int node = tid >> 4, h = tid & (HIDDEN - 1);
    float inv = 1.0f / fmaxf(counts[node], 1.0f);
    const float* sm = summed + (size_t)node * IN_DIM;
    const float* xr = x + (size_t)node * IN_DIM;
    float acc = sb[h];
#pragma unroll
    for (int k = 0; k < IN_DIM; ++k)
        acc += sm[k] * inv * sWl[k * HIDDEN + h] + xr[k] * sWr[k * HIDDEN + h];
    out[tid] = acc;
}

extern "C" void kernel_launch(void* const* d_in, const int* in_sizes, int n_in,
                              void* d_out, int out_size, void* d_ws, size_t ws_size,
                              hipStream_t stream) {
    const float* x   = (const float*)d_in[0];
    const int*   ei  = (const int*)d_in[1];   // [2, E] flat: first E = src, next E = dst
    const float* W_l = (const float*)d_in[2];
    const float* b_l = (const float*)d_in[3];
    const float* W_r = (const float*)d_in[4];
    float* out = (float*)d_out;
    const int* src = ei;
    const int* dst = ei + N_EDGES;

    const size_t region_off = 8192;                               // gcur @0, gover @4096
    const size_t region_sz  = (size_t)NBKT * CAPB * 4;            // 38.44 MB
    const size_t xp_off     = (region_off + region_sz + 31) & ~(size_t)31;
    const size_t xp_sz      = (size_t)N_NODES * 16 * 2;           // 3.2 MB
    const size_t over_off   = xp_off + xp_sz;
    const size_t over_sz    = (size_t)NBKT * CAPO * 4;            // 0.8 MB
    const size_t need = over_off + over_sz;                       // ~42.5 MB

    if (ws_size >= need) {
        int* gcur = (int*)d_ws;
        int* gover = (int*)((char*)d_ws + 4096);
        unsigned* region = (unsigned*)((char*)d_ws + region_off);
        unsigned short* xp = (unsigned short*)((char*)d_ws + xp_off);
        unsigned* over = (unsigned*)((char*)d_ws + over_off);

        // zero both cursor arrays (ws re-poisoned each call)
        hipMemsetAsync(d_ws, 0, 8192, stream);

        bin_edges_xpack<<<NB1, 512, 0, stream>>>(src, dst, x, gcur, gover, region, over, xp);
        bucket_accum_out<<<NBKT, 512, 0, stream>>>(xp, x, gcur, gover, region, over,
                                                   W_l, b_l, W_r, out);
    } else {
        float* summed = (float*)d_ws;
        float* counts = summed + (size_t)N_NODES * IN_DIM;
        hipMemsetAsync(d_ws, 0, (size_t)(N_NODES * IN_DIM + N_NODES) * sizeof(float), stream);
        int threads = 256;
        int eblocks = (N_EDGES + threads - 1) / threads;
        sage_scatter_fb<<<eblocks, threads, 0, stream>>>(x, src, dst, summed, counts);
        int oblocks = (N_NODES * HIDDEN + threads - 1) / threads;
        sage_out_fb<<<oblocks, threads, 0, stream>>>(x, summed, counts, W_l, b_l, W_r, out);
    }
}

// Round 4
// 184.725 us; speedup vs baseline: 3.2688x; 3.2688x over previous
//
#include <hip/hip_runtime.h>

#define N_NODES 100000
#define N_EDGES 6400000
#define IN_DIM 10
#define HIDDEN 16

#define BKT_SHIFT 7
#define BKT_NODES 128                       // nodes per bucket; 1 pass-2 block owns 1 bucket
#define NBKT 782                            // ceil(100000/128)
#define RBIN 11                             // LDS slots per (block,bin): fill λ=5.24, P(>11)~0.8%
#define EPB 4096                            // edges per pass-1 block (8/thread, 2x uint4 pairs)
#define NB1 ((N_EDGES + EPB - 1) / EPB)     // 1563 blocks
#define CAPB 12288                          // region slots per bucket (mean ~10.5k, +11 sigma)
#define CAPO 256                            // overflow slots per bucket (expect ~18/bucket)
#define XELEMS (N_NODES * IN_DIM)
#define XE_PER_BLK ((XELEMS + NB1 - 1) / NB1)  // 640
#define SENT 0xFFFFFFFFu                    // pad sentinel; valid packs < 0x01000000
#define FPS 262144.0f                       // fixed-point scale 2^18
#define FPSI (1.0f / 262144.0f)

typedef unsigned uv4 __attribute__((ext_vector_type(4)));
typedef int iv4 __attribute__((ext_vector_type(4)));
typedef float fv4 __attribute__((ext_vector_type(4)));

__device__ __forceinline__ float bf_lo(unsigned u) { return __uint_as_float(u << 16); }
__device__ __forceinline__ float bf_hi(unsigned u) { return __uint_as_float(u & 0xffff0000u); }
__device__ __forceinline__ int f2i(float f) { return __float2int_rn(f * FPS); }

// ---------------- Pass 1: xpack prologue + bin edges; 16B-aligned drain runs ----------------
__global__ __launch_bounds__(512, 8) void bin_edges_xpack(const int* __restrict__ src,
                                                          const int* __restrict__ dst,
                                                          const float* __restrict__ x,
                                                          int* __restrict__ gcur,
                                                          int* __restrict__ gover,
                                                          unsigned* __restrict__ region,
                                                          unsigned* __restrict__ over,
                                                          unsigned short* __restrict__ xp) {
    __shared__ int lcur[NBKT];               // 3.1 KB
    __shared__ unsigned lbin[NBKT * RBIN];   // 34.4 KB; total 37.5 KB -> 4 blocks/CU
    int t = threadIdx.x;
    for (int b = t; b < NBKT; b += 512) lcur[b] = 0;

    // xpack slice: x fp32 (40B rows) -> bf16 rows at 32B stride (1 line per gather)
    int xbase = blockIdx.x * XE_PER_BLK;
    int xend = min(xbase + XE_PER_BLK, XELEMS);
    for (int e = xbase + t; e < xend; e += 512) {
        int row = e / 10, k = e - row * 10;
        unsigned bits = __float_as_uint(__builtin_nontemporal_load(&x[e]));
        xp[(size_t)row * 16 + k] = (unsigned short)((bits + 0x8000u) >> 16);
    }
    __syncthreads();

    // binning: uint4 edge loads (4 edges/thread/iter), 1 LDS atomic + 1 LDS store per edge
    int base = blockIdx.x * EPB;
    int end = min(base + EPB, N_EDGES);
#define BIN1(ss, dd)                                                                     \
    {                                                                                    \
        int s = (ss), d = (dd);                                                          \
        if ((unsigned)s < N_NODES && (unsigned)d < N_NODES) {                            \
            unsigned pack = (unsigned)s | ((unsigned)(d & (BKT_NODES - 1)) << 17);       \
            int bb = d >> BKT_SHIFT;                                                     \
            int pos = atomicAdd(&lcur[bb], 1);                                           \
            if (pos < RBIN) {                                                            \
                lbin[bb * RBIN + pos] = pack;                                            \
            } else {                                                                     \
                int gg = atomicAdd(&gover[bb], 1);                                       \
                if (gg < CAPO) over[(size_t)bb * CAPO + gg] = pack;                      \
            }                                                                            \
        }                                                                                \
    }
    for (int i = base + (t << 2); i < end; i += 2048) {
        iv4 sv = __builtin_nontemporal_load((const iv4*)(src + i));
        iv4 dv = __builtin_nontemporal_load((const iv4*)(dst + i));
        BIN1(sv.x, dv.x); BIN1(sv.y, dv.y); BIN1(sv.z, dv.z); BIN1(sv.w, dv.w);
    }
    __syncthreads();

    // drain: cursor advances in multiples of 4 slots -> every run is a 16B-aligned
    // uint4-store burst; pad slots carry SENT, filtered free in pass 2 (~1.28x inflate).
    for (int b = t; b < NBKT; b += 512) {
        int f = min(lcur[b], RBIN);
        if (f > 0) {
            int fp = (f + 3) & ~3;                   // 4, 8 or 12
            int g = atomicAdd(&gcur[b], fp);         // stays 4-aligned
            if (g + fp <= CAPB) {
                unsigned* dp = region + (size_t)b * CAPB;
                for (int j = 0; j < fp; j += 4) {
                    uint4 v;
                    v.x = (j + 0 < f) ? lbin[b * RBIN + j + 0] : SENT;
                    v.y = (j + 1 < f) ? lbin[b * RBIN + j + 1] : SENT;
                    v.z = (j + 2 < f) ? lbin[b * RBIN + j + 2] : SENT;
                    v.w = (j + 3 < f) ? lbin[b * RBIN + j + 3] : SENT;
                    *(uint4*)&dp[g + j] = v;         // 16B-aligned store
                }
            }
        }
    }
}

// ---------------- Pass 2: one block per bucket; direct LDS INT-atomic accumulate ----------------
// Round-4 fix: round 3's fp32 LDS atomicAdd lowered to a CAS retry loop (no
// -munsafe-fp-atomics): VALUBusy 1%, all waves parked on lgkmcnt, 467us. Integer
// atomicAdd is a native fire-and-forget ds_add_u32 -> accumulate in FIXED-POINT
// int32 (scale 2^18; sums stay <<2^13, rounding error ~1e-4 vs 0.03125 absmax).
// Slot 10 holds the count. Everything else unchanged from round 3.
#define GATH(r, p, qq)                                                                   \
    {                                                                                    \
        unsigned sid = ((r) == SENT) ? 0u : ((r) & 0x1FFFFu);  /* pads hit hot line */   \
        const unsigned* pp = (const unsigned*)(xp + (size_t)sid * 16);                   \
        p = *(const uint4*)pp;                                                           \
        qq = pp[4];                                                                      \
    }
#define ACCUM(r, p, qq)                                                                  \
    if ((r) != SENT) {                                                                   \
        int nd = ((r) >> 17) & (BKT_NODES - 1);                                          \
        int* a = acci[nd];                                                               \
        atomicAdd(a + 0, f2i(bf_lo(p.x))); atomicAdd(a + 1, f2i(bf_hi(p.x)));            \
        atomicAdd(a + 2, f2i(bf_lo(p.y))); atomicAdd(a + 3, f2i(bf_hi(p.y)));            \
        atomicAdd(a + 4, f2i(bf_lo(p.z))); atomicAdd(a + 5, f2i(bf_hi(p.z)));            \
        atomicAdd(a + 6, f2i(bf_lo(p.w))); atomicAdd(a + 7, f2i(bf_hi(p.w)));            \
        atomicAdd(a + 8, f2i(bf_lo(qq)));  atomicAdd(a + 9, f2i(bf_hi(qq)));             \
        atomicAdd(a + 10, 1);                                                            \
    }

__global__ __launch_bounds__(512, 8) void bucket_accum_out(const unsigned short* __restrict__ xp,
                                                           const float* __restrict__ x,
                                                           const int* __restrict__ gcur,
                                                           const int* __restrict__ gover,
                                                           const unsigned* __restrict__ region,
                                                           const unsigned* __restrict__ over,
                                                           const float* __restrict__ W_l,
                                                           const float* __restrict__ b_l,
                                                           const float* __restrict__ W_r,
                                                           float* __restrict__ out) {
    __shared__ int acci[BKT_NODES][IN_DIM + 1];     // 5.5 KB, stride 11 bank-coprime
    __shared__ float sWl[IN_DIM * HIDDEN], sWr[IN_DIM * HIDDEN], sb[HIDDEN];

    int b = blockIdx.x;
    int t = threadIdx.x;
    for (int i = t; i < BKT_NODES * (IN_DIM + 1); i += 512) ((int*)acci)[i] = 0;
    if (t < IN_DIM * HIDDEN) { sWl[t] = W_l[t]; sWr[t] = W_r[t]; }
    if (t < HIDDEN) sb[t] = b_l[t];
    __syncthreads();

    int n = min(gcur[b], CAPB);                  // multiple of 4 -> clean uint4 walk
    int n4 = n >> 2;
    const uv4* reg4 = (const uv4*)(region + (size_t)b * CAPB);

    // single region walk: 4 independent gathers in flight per uint4, then the adds
    for (int i = t; i < n4; i += 512) {
        uv4 rv = __builtin_nontemporal_load(&reg4[i]);
        uint4 p0, p1, p2, p3; unsigned q0, q1, q2, q3;
        GATH(rv.x, p0, q0); GATH(rv.y, p1, q1); GATH(rv.z, p2, q2); GATH(rv.w, p3, q3);
        ACCUM(rv.x, p0, q0); ACCUM(rv.y, p1, q1); ACCUM(rv.z, p2, q2); ACCUM(rv.w, p3, q3);
    }
    // overflow list (rare, ~18/bucket)
    int m = min(gover[b], CAPO);
    const unsigned* ov = over + (size_t)b * CAPO;
    for (int i = t; i < m; i += 512) {
        unsigned r = __builtin_nontemporal_load(&ov[i]);
        uint4 p; unsigned qq;
        GATH(r, p, qq);
        ACCUM(r, p, qq);
    }
    __syncthreads();

    // fused epilogue: mean + GEMV + bias; exact fp32 root term. 4 threads/node, 4 h each.
    {
        int nl = t >> 2;                         // 0..127
        int hq = (t & 3) << 2;                   // 0,4,8,12
        int node = b * BKT_NODES + nl;
        if (node < N_NODES) {
            float cnt = (float)acci[nl][IN_DIM];
            float inv = FPSI / fmaxf(cnt, 1.0f); // fixed-point unscale fused into mean
            const float* xr = x + (size_t)node * IN_DIM;
            float o0 = sb[hq], o1 = sb[hq + 1], o2 = sb[hq + 2], o3 = sb[hq + 3];
#pragma unroll
            for (int k = 0; k < IN_DIM; ++k) {
                float m2 = (float)acci[nl][k] * inv;  // LDS broadcast across the 4 lanes
                float xk = xr[k];                // same line for 4 lanes -> 1 req
                const float* wl = &sWl[k * HIDDEN + hq];
                const float* wr = &sWr[k * HIDDEN + hq];
                o0 += m2 * wl[0] + xk * wr[0];
                o1 += m2 * wl[1] + xk * wr[1];
                o2 += m2 * wl[2] + xk * wr[2];
                o3 += m2 * wl[3] + xk * wr[3];
            }
            fv4 o = {o0, o1, o2, o3};
            __builtin_nontemporal_store(o, (fv4*)(out + (size_t)node * HIDDEN + hq));
        }
    }
}

// ---------------- fallback (round-1 style, correct, slow) for tiny ws ----------------
__global__ void sage_scatter_fb(const float* __restrict__ x, const int* __restrict__ src,
                                const int* __restrict__ dst, float* __restrict__ summed,
                                float* __restrict__ counts) {
    int e = blockIdx.x * blockDim.x + threadIdx.x;
    if (e >= N_EDGES) return;
    int s = src[e], d = dst[e];
    if ((unsigned)s >= N_NODES || (unsigned)d >= N_NODES) return;
    const float* xs = x + (size_t)s * IN_DIM;
    float* sm = summed + (size_t)d * IN_DIM;
#pragma unroll
    for (int k = 0; k < IN_DIM; ++k) atomicAdd(&sm[k], xs[k]);
    atomicAdd(&counts[d], 1.0f);
}

__global__ void sage_out_fb(const float* __restrict__ x, const float* __restrict__ summed,
                            const float* __restrict__ counts, const float* __restrict__ W_l,
                            const float* __restrict__ b_l, const float* __restrict__ W_r,
                            float* __restrict__ out) {
    __shared__ float sWl[IN_DIM * HIDDEN], sWr[IN_DIM * HIDDEN], sb[HIDDEN];
    int t = threadIdx.x;
    if (t < IN_DIM * HIDDEN) { sWl[t] = W_l[t]; sWr[t] = W_r[t]; }
    if (t < HIDDEN) sb[t] = b_l[t];
    __syncthreads();
    int tid = blockIdx.x * blockDim.x + t;
    if (tid >= N_NODES * HIDDEN) return;
    int node = tid >> 4, h = tid & (HIDDEN - 1);
    float inv = 1.0f / fmaxf(counts[node], 1.0f);
    const float* sm = summed + (size_t)node * IN_DIM;
    const float* xr = x + (size_t)node * IN_DIM;
    float acc = sb[h];
#pragma unroll
    for (int k = 0; k < IN_DIM; ++k)
        acc += sm[k] * inv * sWl[k * HIDDEN + h] + xr[k] * sWr[k * HIDDEN + h];
    out[tid] = acc;
}

extern "C" void kernel_launch(void* const* d_in, const int* in_sizes, int n_in,
                              void* d_out, int out_size, void* d_ws, size_t ws_size,
                              hipStream_t stream) {
    const float* x   = (const float*)d_in[0];
    const int*   ei  = (const int*)d_in[1];   // [2, E] flat: first E = src, next E = dst
    const float* W_l = (const float*)d_in[2];
    const float* b_l = (const float*)d_in[3];
    const float* W_r = (const float*)d_in[4];
    float* out = (float*)d_out;
    const int* src = ei;
    const int* dst = ei + N_EDGES;

    const size_t region_off = 8192;                               // gcur @0, gover @4096
    const size_t region_sz  = (size_t)NBKT * CAPB * 4;            // 38.44 MB
    const size_t xp_off     = (region_off + region_sz + 31) & ~(size_t)31;
    const size_t xp_sz      = (size_t)N_NODES * 16 * 2;           // 3.2 MB
    const size_t over_off   = xp_off + xp_sz;
    const size_t over_sz    = (size_t)NBKT * CAPO * 4;            // 0.8 MB
    const size_t need = over_off + over_sz;                       // ~42.5 MB

    if (ws_size >= need) {
        int* gcur = (int*)d_ws;
        int* gover = (int*)((char*)d_ws + 4096);
        unsigned* region = (unsigned*)((char*)d_ws + region_off);
        unsigned short* xp = (unsigned short*)((char*)d_ws + xp_off);
        unsigned* over = (unsigned*)((char*)d_ws + over_off);

        // zero both cursor arrays (ws re-poisoned each call)
        hipMemsetAsync(d_ws, 0, 8192, stream);

        bin_edges_xpack<<<NB1, 512, 0, stream>>>(src, dst, x, gcur, gover, region, over, xp);
        bucket_accum_out<<<NBKT, 512, 0, stream>>>(xp, x, gcur, gover, region, over,
                                                   W_l, b_l, W_r, out);
    } else {
        float* summed = (float*)d_ws;
        float* counts = summed + (size_t)N_NODES * IN_DIM;
        hipMemsetAsync(d_ws, 0, (size_t)(N_NODES * IN_DIM + N_NODES) * sizeof(float), stream);
        int threads = 256;
        int eblocks = (N_EDGES + threads - 1) / threads;
        sage_scatter_fb<<<eblocks, threads, 0, stream>>>(x, src, dst, summed, counts);
        int oblocks = (N_NODES * HIDDEN + threads - 1) / threads;
        sage_out_fb<<<oblocks, threads, 0, stream>>>(x, summed, counts, W_l, b_l, W_r, out);
    }
}

// Round 5
// 180.970 us; speedup vs baseline: 3.3366x; 1.0208x over previous
//
#include <hip/hip_runtime.h>

#define N_NODES 100000
#define N_EDGES 6400000
#define IN_DIM 10
#define HIDDEN 16

#define BKT_SHIFT 8
#define BKT_NODES 256                       // nodes per bucket (region granularity)
#define NBKT 391                            // ceil(100000/256)
#define RBIN 40                             // LDS slots per (block,bin): fill λ=26.2, P(>40)~0.5%
#define EPB 10240                           // edges per pass-1 block (20/thread, 5x uint4 pairs)
#define NB1 ((N_EDGES + EPB - 1) / EPB)     // 625 blocks (exact: 625*10240 = 6.4M)
#define CAPB 24576                          // region slots per bucket (mean padded ~20.8k, +19 sigma)
#define CAPO 256                            // overflow slots per bucket (expect ~3/bucket)
#define HNODES 128                          // nodes per pass-2 block (half bucket)
#define XELEMS (N_NODES * IN_DIM)
#define XE_PER_BLK ((XELEMS + NB1 - 1) / NB1)  // 1600
#define SENT 0xFFFFFFFFu                    // pad sentinel; (SENT>>24)=255 != any half
#define FPS 262144.0f                       // fixed-point scale 2^18
#define FPSI (1.0f / 262144.0f)

typedef unsigned uv4 __attribute__((ext_vector_type(4)));
typedef int iv4 __attribute__((ext_vector_type(4)));
typedef float fv4 __attribute__((ext_vector_type(4)));

__device__ __forceinline__ float bf_lo(unsigned u) { return __uint_as_float(u << 16); }
__device__ __forceinline__ float bf_hi(unsigned u) { return __uint_as_float(u & 0xffff0000u); }
__device__ __forceinline__ int f2i(float f) { return __float2int_rn(f * FPS); }

// ---------------- Pass 1: xpack prologue + bin edges; FULL-LINE drain runs ----------------
// Round-5 fix: round 3/4's pad-4 drain wrote 16-48B runs; adjacent runs of one bucket
// come from blocks on different XCDs -> the same 64B line partially dirty in multiple
// non-coherent L2s -> partial-line HBM RMW (WRITE 59.5MB vs 36 ideal, 25% HBM eff).
// Back to pad-16 (64B-aligned, 64B-multiple runs, amp 1.0) at lambda=26.2 so the pad
// inflation stays 27%: region write = 625*391*33.3*4 ~ 32.5MB, all full lines.
__global__ __launch_bounds__(512, 8) void bin_edges_xpack(const int* __restrict__ src,
                                                          const int* __restrict__ dst,
                                                          const float* __restrict__ x,
                                                          int* __restrict__ gcur,
                                                          int* __restrict__ gover,
                                                          unsigned* __restrict__ region,
                                                          unsigned* __restrict__ over,
                                                          unsigned short* __restrict__ xp) {
    __shared__ int lcur[NBKT];               // 1.6 KB
    __shared__ unsigned lbin[NBKT * RBIN];   // 62.6 KB; total ~64 KB -> 2 blocks/CU
    int t = threadIdx.x;
    for (int b = t; b < NBKT; b += 512) lcur[b] = 0;

    // xpack slice: x fp32 (40B rows) -> bf16 rows at 32B stride (1 line per gather)
    int xbase = blockIdx.x * XE_PER_BLK;
    int xend = min(xbase + XE_PER_BLK, XELEMS);
    for (int e = xbase + t; e < xend; e += 512) {
        int row = e / 10, k = e - row * 10;
        unsigned bits = __float_as_uint(__builtin_nontemporal_load(&x[e]));
        xp[(size_t)row * 16 + k] = (unsigned short)((bits + 0x8000u) >> 16);
    }
    __syncthreads();

    // binning: uint4 edge loads (4 edges/thread/iter), 1 LDS atomic + 1 LDS store per edge
    int base = blockIdx.x * EPB;
    int end = min(base + EPB, N_EDGES);
#define BIN1(ss, dd)                                                                     \
    {                                                                                    \
        int s = (ss), d = (dd);                                                          \
        if ((unsigned)s < N_NODES && (unsigned)d < N_NODES) {                            \
            unsigned pack = (unsigned)s | ((unsigned)(d & (BKT_NODES - 1)) << 17);       \
            int bb = d >> BKT_SHIFT;                                                     \
            int pos = atomicAdd(&lcur[bb], 1);                                           \
            if (pos < RBIN) {                                                            \
                lbin[bb * RBIN + pos] = pack;                                            \
            } else {                                                                     \
                int gg = atomicAdd(&gover[bb], 1);                                       \
                if (gg < CAPO) over[(size_t)bb * CAPO + gg] = pack;                      \
            }                                                                            \
        }                                                                                \
    }
    for (int i = base + (t << 2); i < end; i += 2048) {
        iv4 sv = __builtin_nontemporal_load((const iv4*)(src + i));
        iv4 dv = __builtin_nontemporal_load((const iv4*)(dst + i));
        BIN1(sv.x, dv.x); BIN1(sv.y, dv.y); BIN1(sv.z, dv.z); BIN1(sv.w, dv.w);
    }
    __syncthreads();

    // drain: cursor advances in multiples of 16 slots -> every run is a 64B-aligned
    // full-line burst (uint4 stores); pad slots carry SENT, filtered free in pass 2.
    for (int b = t; b < NBKT; b += 512) {
        int f = min(lcur[b], RBIN);
        if (f > 0) {
            int fp = (f + 15) & ~15;                 // 16, 32 or 48
            int g = atomicAdd(&gcur[b], fp);         // stays 16-aligned
            if (g + fp <= CAPB) {
                unsigned* dp = region + (size_t)b * CAPB;
                for (int j = 0; j < fp; j += 4) {
                    uint4 v;
                    v.x = (j + 0 < f) ? lbin[b * RBIN + j + 0] : SENT;
                    v.y = (j + 1 < f) ? lbin[b * RBIN + j + 1] : SENT;
                    v.z = (j + 2 < f) ? lbin[b * RBIN + j + 2] : SENT;
                    v.w = (j + 3 < f) ? lbin[b * RBIN + j + 3] : SENT;
                    *(uint4*)&dp[g + j] = v;         // 16B-aligned store
                }
            }
        }
    }
}

// ---------------- Pass 2: 2 blocks per bucket (node-bit split); LDS INT-atomic accumulate ----
// Each block owns 128 nodes = one half (record bit 24) of a 256-node bucket and walks the
// bucket's full region stream once, filtering by a single compare (SENT>>24=255 rejected
// free). The pair is co-located on one XCD via chunked id decode so the twin's walk hits
// local L2. Non-matching lanes gather xp line 0 (hot) to keep 4 gathers in flight.
// Fixed-point int32 accumulate (scale 2^18): native fire-and-forget ds_add_u32.
#define GSEL(r) ((((r) >> 24) == uhalf) ? ((r) & 0x1FFFFu) : 0u)
#define GATH(r, p, qq)                                                                   \
    {                                                                                    \
        unsigned sid = GSEL(r);                                                          \
        const unsigned* pp = (const unsigned*)(xp + (size_t)sid * 16);                   \
        p = *(const uint4*)pp;                                                           \
        qq = pp[4];                                                                      \
    }
#define ACCUM(r, p, qq)                                                                  \
    if (((r) >> 24) == uhalf) {                                                          \
        int nd = ((r) >> 17) & (HNODES - 1);                                             \
        int* a = acci[nd];                                                               \
        atomicAdd(a + 0, f2i(bf_lo(p.x))); atomicAdd(a + 1, f2i(bf_hi(p.x)));            \
        atomicAdd(a + 2, f2i(bf_lo(p.y))); atomicAdd(a + 3, f2i(bf_hi(p.y)));            \
        atomicAdd(a + 4, f2i(bf_lo(p.z))); atomicAdd(a + 5, f2i(bf_hi(p.z)));            \
        atomicAdd(a + 6, f2i(bf_lo(p.w))); atomicAdd(a + 7, f2i(bf_hi(p.w)));            \
        atomicAdd(a + 8, f2i(bf_lo(qq)));  atomicAdd(a + 9, f2i(bf_hi(qq)));             \
        atomicAdd(a + 10, 1);                                                            \
    }

__global__ __launch_bounds__(512, 8) void bucket_accum_out(const unsigned short* __restrict__ xp,
                                                           const float* __restrict__ x,
                                                           const int* __restrict__ gcur,
                                                           const int* __restrict__ gover,
                                                           const unsigned* __restrict__ region,
                                                           const unsigned* __restrict__ over,
                                                           const float* __restrict__ W_l,
                                                           const float* __restrict__ b_l,
                                                           const float* __restrict__ W_r,
                                                           float* __restrict__ out) {
    __shared__ int acci[HNODES][IN_DIM + 1];        // 5.5 KB, stride 11 bank-coprime
    __shared__ float sWl[IN_DIM * HIDDEN], sWr[IN_DIM * HIDDEN], sb[HIDDEN];

    // chunked decode: ids with equal (id&7) land on one XCD (round-robin heuristic);
    // chunk size 98 is even -> both halves of a bucket stay in the same chunk.
    int id = blockIdx.x;
    int item = (id & 7) * 98 + (id >> 3);
    if (item >= 2 * NBKT) return;                // uniform across block: safe
    int b = item >> 1;
    unsigned uhalf = (unsigned)(item & 1);

    int t = threadIdx.x;
    for (int i = t; i < HNODES * (IN_DIM + 1); i += 512) ((int*)acci)[i] = 0;
    if (t < IN_DIM * HIDDEN) { sWl[t] = W_l[t]; sWr[t] = W_r[t]; }
    if (t < HIDDEN) sb[t] = b_l[t];
    __syncthreads();

    int n = min(gcur[b], CAPB);                  // multiple of 16 -> clean uint4 walk
    int n4 = n >> 2;
    const uv4* reg4 = (const uv4*)(region + (size_t)b * CAPB);

    // single stream walk: 4 (predicated) gathers in flight per uint4, then the adds
    for (int i = t; i < n4; i += 512) {
        uv4 rv = __builtin_nontemporal_load(&reg4[i]);
        uint4 p0, p1, p2, p3; unsigned q0, q1, q2, q3;
        GATH(rv.x, p0, q0); GATH(rv.y, p1, q1); GATH(rv.z, p2, q2); GATH(rv.w, p3, q3);
        ACCUM(rv.x, p0, q0); ACCUM(rv.y, p1, q1); ACCUM(rv.z, p2, q2); ACCUM(rv.w, p3, q3);
    }
    // overflow list (rare, ~3/bucket)
    int m = min(gover[b], CAPO);
    const unsigned* ov = over + (size_t)b * CAPO;
    for (int i = t; i < m; i += 512) {
        unsigned r = __builtin_nontemporal_load(&ov[i]);
        uint4 p; unsigned qq;
        GATH(r, p, qq);
        ACCUM(r, p, qq);
    }
    __syncthreads();

    // fused epilogue: mean + GEMV + bias; exact fp32 root term. 4 threads/node, 4 h each.
    {
        int nl = t >> 2;                         // 0..127
        int hq = (t & 3) << 2;                   // 0,4,8,12
        int node = b * BKT_NODES + (int)uhalf * HNODES + nl;
        if (node < N_NODES) {
            float cnt = (float)acci[nl][IN_DIM];
            float inv = FPSI / fmaxf(cnt, 1.0f); // fixed-point unscale fused into mean
            const float* xr = x + (size_t)node * IN_DIM;
            float o0 = sb[hq], o1 = sb[hq + 1], o2 = sb[hq + 2], o3 = sb[hq + 3];
#pragma unroll
            for (int k = 0; k < IN_DIM; ++k) {
                float m2 = (float)acci[nl][k] * inv;  // LDS broadcast across the 4 lanes
                float xk = xr[k];                // same line for 4 lanes -> 1 req
                const float* wl = &sWl[k * HIDDEN + hq];
                const float* wr = &sWr[k * HIDDEN + hq];
                o0 += m2 * wl[0] + xk * wr[0];
                o1 += m2 * wl[1] + xk * wr[1];
                o2 += m2 * wl[2] + xk * wr[2];
                o3 += m2 * wl[3] + xk * wr[3];
            }
            fv4 o = {o0, o1, o2, o3};
            __builtin_nontemporal_store(o, (fv4*)(out + (size_t)node * HIDDEN + hq));
        }
    }
}

// ---------------- fallback (round-1 style, correct, slow) for tiny ws ----------------
__global__ void sage_scatter_fb(const float* __restrict__ x, const int* __restrict__ src,
                                const int* __restrict__ dst, float* __restrict__ summed,
                                float* __restrict__ counts) {
    int e = blockIdx.x * blockDim.x + threadIdx.x;
    if (e >= N_EDGES) return;
    int s = src[e], d = dst[e];
    if ((unsigned)s >= N_NODES || (unsigned)d >= N_NODES) return;
    const float* xs = x + (size_t)s * IN_DIM;
    float* sm = summed + (size_t)d * IN_DIM;
#pragma unroll
    for (int k = 0; k < IN_DIM; ++k) atomicAdd(&sm[k], xs[k]);
    atomicAdd(&counts[d], 1.0f);
}

__global__ void sage_out_fb(const float* __restrict__ x, const float* __restrict__ summed,
                            const float* __restrict__ counts, const float* __restrict__ W_l,
                            const float* __restrict__ b_l, const float* __restrict__ W_r,
                            float* __restrict__ out) {
    __shared__ float sWl[IN_DIM * HIDDEN], sWr[IN_DIM * HIDDEN], sb[HIDDEN];
    int t = threadIdx.x;
    if (t < IN_DIM * HIDDEN) { sWl[t] = W_l[t]; sWr[t] = W_r[t]; }
    if (t < HIDDEN) sb[t] = b_l[t];
    __syncthreads();
    int tid = blockIdx.x * blockDim.x + t;
    if (tid >= N_NODES * HIDDEN) return;
    int node = tid >> 4, h = tid & (HIDDEN - 1);
    float inv = 1.0f / fmaxf(counts[node], 1.0f);
    const float* sm = summed + (size_t)node * IN_DIM;
    const float* xr = x + (size_t)node * IN_DIM;
    float acc = sb[h];
#pragma unroll
    for (int k = 0; k < IN_DIM; ++k)
        acc += sm[k] * inv * sWl[k * HIDDEN + h] + xr[k] * sWr[k * HIDDEN + h];
    out[tid] = acc;
}

extern "C" void kernel_launch(void* const* d_in, const int* in_sizes, int n_in,
                              void* d_out, int out_size, void* d_ws, size_t ws_size,
                              hipStream_t stream) {
    const float* x   = (const float*)d_in[0];
    const int*   ei  = (const int*)d_in[1];   // [2, E] flat: first E = src, next E = dst
    const float* W_l = (const float*)d_in[2];
    const float* b_l = (const float*)d_in[3];
    const float* W_r = (const float*)d_in[4];
    float* out = (float*)d_out;
    const int* src = ei;
    const int* dst = ei + N_EDGES;

    const size_t region_off = 8192;                               // gcur @0, gover @4096
    const size_t region_sz  = (size_t)NBKT * CAPB * 4;            // 38.44 MB
    const size_t xp_off     = (region_off + region_sz + 31) & ~(size_t)31;
    const size_t xp_sz      = (size_t)N_NODES * 16 * 2;           // 3.2 MB
    const size_t over_off   = xp_off + xp_sz;
    const size_t over_sz    = (size_t)NBKT * CAPO * 4;            // 0.4 MB
    const size_t need = over_off + over_sz;                       // ~42.1 MB

    if (ws_size >= need) {
        int* gcur = (int*)d_ws;
        int* gover = (int*)((char*)d_ws + 4096);
        unsigned* region = (unsigned*)((char*)d_ws + region_off);
        unsigned short* xp = (unsigned short*)((char*)d_ws + xp_off);
        unsigned* over = (unsigned*)((char*)d_ws + over_off);

        // zero both cursor arrays (ws re-poisoned each call)
        hipMemsetAsync(d_ws, 0, 8192, stream);

        bin_edges_xpack<<<NB1, 512, 0, stream>>>(src, dst, x, gcur, gover, region, over, xp);
        bucket_accum_out<<<784, 512, 0, stream>>>(xp, x, gcur, gover, region, over,
                                                  W_l, b_l, W_r, out);
    } else {
        float* summed = (float*)d_ws;
        float* counts = summed + (size_t)N_NODES * IN_DIM;
        hipMemsetAsync(d_ws, 0, (size_t)(N_NODES * IN_DIM + N_NODES) * sizeof(float), stream);
        int threads = 256;
        int eblocks = (N_EDGES + threads - 1) / threads;
        sage_scatter_fb<<<eblocks, threads, 0, stream>>>(x, src, dst, summed, counts);
        int oblocks = (N_NODES * HIDDEN + threads - 1) / threads;
        sage_out_fb<<<oblocks, threads, 0, stream>>>(x, summed, counts, W_l, b_l, W_r, out);
    }
}